// Round 2
// baseline (734.941 us; speedup 1.0000x reference)
//
#include <hip/hip_runtime.h>
#include <hip/hip_bf16.h>

// UnimodalNormal: fused matvec-heads + normal-CDF histogram + row-normalize.
// B=262144, D=512, C=100. Memory-bound on reading x (537 MB); one wave per row.

constexpr int D_DIM = 512;
constexpr int C_BINS = 100;
constexpr float MIN_SIGMA = 0.01f;
constexpr float MAX_SIGMA = 100.0f;
constexpr float BINS_LIMIT = 1.0f;

__global__ __launch_bounds__(256) void unimodal_normal_kernel(
    const float* __restrict__ x,
    const float* __restrict__ w_mu,
    const float* __restrict__ b_mu,
    const float* __restrict__ w_sig,
    const float* __restrict__ b_sig,
    float* __restrict__ out,
    int rows)
{
    const int lane = threadIdx.x & 63;
    const int waves_per_block = blockDim.x >> 6;
    const int wid = blockIdx.x * waves_per_block + (threadIdx.x >> 6);
    const int nwaves = gridDim.x * waves_per_block;

    // Per-lane weight fragments: lane covers elements [lane*4, lane*4+4) and
    // [256+lane*4, ...). 2 KB per vector -> L1-resident for all waves.
    const float4 wm0 = *reinterpret_cast<const float4*>(w_mu + lane * 4);
    const float4 wm1 = *reinterpret_cast<const float4*>(w_mu + 256 + lane * 4);
    const float4 ws0 = *reinterpret_cast<const float4*>(w_sig + lane * 4);
    const float4 ws1 = *reinterpret_cast<const float4*>(w_sig + 256 + lane * 4);
    const float bmu = b_mu[0];
    const float bsg = b_sig[0];

    const float inv_sqrt2 = 0.70710678118654752440f;

    for (int row = wid; row < rows; row += nwaves) {
        const float* xr = x + (size_t)row * D_DIM;
        const float4 xa = *reinterpret_cast<const float4*>(xr + lane * 4);
        const float4 xb = *reinterpret_cast<const float4*>(xr + 256 + lane * 4);

        // Two dot products, per-lane partials.
        float dm = xa.x * wm0.x;
        dm = fmaf(xa.y, wm0.y, dm);
        dm = fmaf(xa.z, wm0.z, dm);
        dm = fmaf(xa.w, wm0.w, dm);
        dm = fmaf(xb.x, wm1.x, dm);
        dm = fmaf(xb.y, wm1.y, dm);
        dm = fmaf(xb.z, wm1.z, dm);
        dm = fmaf(xb.w, wm1.w, dm);

        float ds = xa.x * ws0.x;
        ds = fmaf(xa.y, ws0.y, ds);
        ds = fmaf(xa.z, ws0.z, ds);
        ds = fmaf(xa.w, ws0.w, ds);
        ds = fmaf(xb.x, ws1.x, ds);
        ds = fmaf(xb.y, ws1.y, ds);
        ds = fmaf(xb.z, ws1.z, ds);
        ds = fmaf(xb.w, ws1.w, ds);

        // Wave-64 butterfly reduction of both sums.
        #pragma unroll
        for (int off = 32; off > 0; off >>= 1) {
            dm += __shfl_xor(dm, off, 64);
            ds += __shfl_xor(ds, off, 64);
        }

        // Heads.
        const float mu = tanhf(dm + bmu);
        const float s = ds + bsg;
        // softplus = log1p(exp(s)); for large s it is s (exp overflows).
        const float sp = (s > 20.0f) ? s : log1pf(__expf(s));
        const float sig = fminf(fmaxf(sp, MIN_SIGMA), MAX_SIGMA);
        const float a = inv_sqrt2 / sig; // fold 1/sqrt(2) into 1/sigma

        // Row sum telescopes: sum(probs) = cdf[C]-cdf[0]; 0.5 factors cancel.
        const float e_lo = erff((-BINS_LIMIT - mu) * a);
        const float e_hi = erff((BINS_LIMIT - mu) * a);
        const float inv_den = 1.0f / (e_hi - e_lo);

        float* orow = out + (size_t)row * C_BINS;
        #pragma unroll
        for (int k = 0; k < 2; ++k) {
            const int c = lane + k * 64;
            if (c < C_BINS) {
                const float t0 = (float)c * (2.0f * BINS_LIMIT / C_BINS) - BINS_LIMIT;
                const float t1 = (float)(c + 1) * (2.0f * BINS_LIMIT / C_BINS) - BINS_LIMIT;
                const float p = (erff((t1 - mu) * a) - erff((t0 - mu) * a)) * inv_den;
                orow[c] = p;
            }
        }
    }
}

extern "C" void kernel_launch(void* const* d_in, const int* in_sizes, int n_in,
                              void* d_out, int out_size, void* d_ws, size_t ws_size,
                              hipStream_t stream) {
    const float* x     = (const float*)d_in[0];
    const float* w_mu  = (const float*)d_in[1];
    const float* b_mu  = (const float*)d_in[2];
    const float* w_sig = (const float*)d_in[3];
    const float* b_sig = (const float*)d_in[4];
    float* out = (float*)d_out;

    const int rows = in_sizes[0] / D_DIM;

    const int block = 256;
    const int grid = 2048; // 8192 waves, grid-stride over rows
    unimodal_normal_kernel<<<grid, block, 0, stream>>>(
        x, w_mu, b_mu, w_sig, b_sig, out, rows);
}